// Round 8
// baseline (577.046 us; speedup 1.0000x reference)
//
#include <hip/hip_runtime.h>
#include <hip/hip_bf16.h>
#include <math.h>

#define B_ROWS 65536
#define D_DIM 256
#define C_DIM 128
#define H_DIM 1024

typedef __bf16 bf16x8 __attribute__((ext_vector_type(8)));
typedef float f32x4 __attribute__((ext_vector_type(4)));
typedef short short8 __attribute__((ext_vector_type(8)));

__device__ __forceinline__ unsigned short f2bf(float f) {
    unsigned int u = __float_as_uint(f);
    u += 0x7fffu + ((u >> 16) & 1u);
    return (unsigned short)(u >> 16);
}

__device__ __forceinline__ void gl2lds16(const void* g, void* l) {
    __builtin_amdgcn_global_load_lds(
        (const __attribute__((address_space(1))) unsigned int*)g,
        (__attribute__((address_space(3))) unsigned int*)l, 16, 0, 0);
}

// Opaque LDS read via a proper address_space(3) pointer. Compiler cannot see
// the dependency on outstanding global_load_lds -> no conservative vmcnt(0)
// drains; correctness comes from explicit barriers + counted vmcnt/lgkmcnt.
__device__ __forceinline__ bf16x8 ds_read_b128_asm(const short* p) {
    bf16x8 r;
    asm volatile("ds_read_b128 %0, %1"
                 : "=v"(r)
                 : "v"((const __attribute__((address_space(3))) short*)p));
    return r;
}

// XCD-aware swizzle helpers
__device__ __forceinline__ int xcd_swz(int id, int nwg) {
    int xcd = id & 7, lid = id >> 3;
    int q = nwg >> 3, r = nwg & 7;
    return (xcd < r ? xcd * (q + 1) : r * (q + 1) + (xcd - r) * q) + lid;
}

__device__ __forceinline__ void swizzle_mn(int id, int mtiles, int& m, int& n) {
    if ((mtiles & 7) == 0) {
        int g = id >> 6, r = id & 63;
        m = g * 8 + (r & 7);
        n = r >> 3;
    } else {
        m = id >> 3;
        n = id & 7;
    }
}

// ===========================================================================
// Merged prep: 4 weight transposes + b3 concat + A-prep, one launch.
// ===========================================================================
__global__ __launch_bounds__(256) void prep_all(
    const float* __restrict__ W1, const float* __restrict__ W2,
    const float* __restrict__ Ws, const float* __restrict__ Wt,
    const float* __restrict__ bs, const float* __restrict__ bt,
    const float* __restrict__ x, const float* __restrict__ cond,
    short* __restrict__ W1T, short* __restrict__ W2T, short* __restrict__ W3T,
    float* __restrict__ b3, short* __restrict__ A) {
    int t = blockIdx.x * 256 + threadIdx.x;
    if (t < 196864) {
        short8 o;
        if (t < 32768) {
            int n = t >> 5, k0 = (t & 31) << 3;
#pragma unroll
            for (int j = 0; j < 8; ++j) o[j] = (short)f2bf(W1[(size_t)(k0 + j) * 1024 + n]);
            *(short8*)&W1T[(size_t)n * 256 + k0] = o;
        } else if (t < 163840) {
            int u = t - 32768;
            int n = u >> 7, k0 = (u & 127) << 3;
#pragma unroll
            for (int j = 0; j < 8; ++j) o[j] = (short)f2bf(W2[(size_t)(k0 + j) * 1024 + n]);
            *(short8*)&W2T[(size_t)n * 1024 + k0] = o;
        } else if (t < 180224) {
            int u = t - 163840;
            int n = u >> 7, k0 = (u & 127) << 3;
#pragma unroll
            for (int j = 0; j < 8; ++j) o[j] = (short)f2bf(Ws[(size_t)(k0 + j) * 128 + n]);
            *(short8*)&W3T[(size_t)n * 1024 + k0] = o;
        } else if (t < 196608) {
            int u = t - 180224;
            int n = u >> 7, k0 = (u & 127) << 3;
#pragma unroll
            for (int j = 0; j < 8; ++j) o[j] = (short)f2bf(Wt[(size_t)(k0 + j) * 128 + n]);
            *(short8*)&W3T[131072 + (size_t)n * 1024 + k0] = o;
        } else {
            int i = t - 196608;
            b3[i] = (i < 128) ? bs[i] : bt[i - 128];
        }
    } else {
        int u = t - 196864;
        int m = u >> 5, seg = u & 31;
        short8 o;
        if (seg < 16) {
            const float4* p = (const float4*)(x + (size_t)m * 256 + seg * 16);
            float4 a = p[0], b = p[1], c = p[2], d = p[3];
            o[0] = (short)f2bf(a.x); o[1] = (short)f2bf(a.z);
            o[2] = (short)f2bf(b.x); o[3] = (short)f2bf(b.z);
            o[4] = (short)f2bf(c.x); o[5] = (short)f2bf(c.z);
            o[6] = (short)f2bf(d.x); o[7] = (short)f2bf(d.z);
        } else {
            const float4* p = (const float4*)(cond + (size_t)m * 128 + (seg - 16) * 8);
            float4 a = p[0], b = p[1];
            o[0] = (short)f2bf(a.x); o[1] = (short)f2bf(a.y);
            o[2] = (short)f2bf(a.z); o[3] = (short)f2bf(a.w);
            o[4] = (short)f2bf(b.x); o[5] = (short)f2bf(b.y);
            o[6] = (short)f2bf(b.z); o[7] = (short)f2bf(b.w);
        }
        *(short8*)&A[(size_t)m * 256 + seg * 8] = o;
    }
}

// Generic fallback GEMM (128x128 tile), used only if RP % 256 != 0.
__global__ __launch_bounds__(256) void gemm_tn(
    const short* __restrict__ A, const short* __restrict__ Bw,
    const float* __restrict__ bias, unsigned short* __restrict__ Cout,
    int mtiles, int N, int K) {
    constexpr int BK = 64;
    __shared__ __align__(16) short As[128 * BK];
    __shared__ __align__(16) short Bs[128 * BK];
    const int tid = threadIdx.x;
    const int lane = tid & 63;
    const int wave = tid >> 6;
    int mt, nt;
    swizzle_mn(blockIdx.x, mtiles, mt, nt);
    const int tm = mt * 128, tn = nt * 128;
    const int mo = (wave >> 1) * 64;
    const int no = (wave & 1) * 64;

    f32x4 acc[4][4];
#pragma unroll
    for (int i = 0; i < 4; ++i)
#pragma unroll
        for (int j = 0; j < 4; ++j) acc[i][j] = f32x4{0.f, 0.f, 0.f, 0.f};

    const int srow = lane >> 3;
    const int skb = (lane & 7) ^ srow;

    for (int kc = 0; kc < K; kc += BK) {
        __syncthreads();
#pragma unroll
        for (int i = 0; i < 4; ++i) {
            int c = wave * 4 + i;
            int row = c * 8 + srow;
            gl2lds16(A + (size_t)(tm + row) * K + kc + skb * 8, &As[c * 512]);
            gl2lds16(Bw + (size_t)(tn + row) * K + kc + skb * 8, &Bs[c * 512]);
        }
        __syncthreads();
#pragma unroll
        for (int kk = 0; kk < 2; ++kk) {
            bf16x8 af[4], bfr[4];
            int kb = kk * 4 + (lane >> 4);
#pragma unroll
            for (int t = 0; t < 4; ++t) {
                int r = mo + t * 16 + (lane & 15);
                af[t] = *(const bf16x8*)&As[r * BK + ((kb ^ (r & 7)) << 3)];
                int n = no + t * 16 + (lane & 15);
                bfr[t] = *(const bf16x8*)&Bs[n * BK + ((kb ^ (n & 7)) << 3)];
            }
#pragma unroll
            for (int i = 0; i < 4; ++i)
#pragma unroll
                for (int j = 0; j < 4; ++j)
                    acc[i][j] = __builtin_amdgcn_mfma_f32_16x16x32_bf16(
                        af[i], bfr[j], acc[i][j], 0, 0, 0);
        }
    }

#pragma unroll
    for (int j = 0; j < 4; ++j) {
        int col = tn + no + j * 16 + (lane & 15);
        float bb = bias[col];
#pragma unroll
        for (int i = 0; i < 4; ++i) {
            int row0 = tm + mo + i * 16 + ((lane >> 4) << 2);
            f32x4 v = acc[i][j];
#pragma unroll
            for (int rr = 0; rr < 4; ++rr)
                Cout[(size_t)(row0 + rr) * N + col] = f2bf(fmaxf(v[rr] + bb, 0.f));
        }
    }
}

// ===========================================================================
// Pipelined GEMM (templated K), 256x256 tile, BK=64, 8 waves (2M x 4N).
// Round-8 change: parity-double fragment registers, issue ds_reads BEFORE
// the MFMA cluster, counted lgkmcnt.
//   slot s: [vmcnt?(odd) -> BAR -> stage -> ds_reads(af set ph&1; ph0 also
//            bfr set w&1) -> lgkmcnt(N_s) -> MFMA(af set (ph&1)^1,
//            bfr set w&1 (ph0: (w&1)^1))]
// N_s = reads issued this slot (12 at ph0, 4 else); the counted wait covers
// exactly the previous slot's reads (FIFO lgkm retirement), which had a full
// MFMA cluster to complete -> LDS pipe streams during the matrix pipe.
// af sets alternate by slot parity (4 slots/window -> ph&1); bfr lives a full
// window, last used at ph0 of the NEXT window where the next B reads issue ->
// window-parity sets. All indices compile-time (loops unrolled).
// vmcnt ledger / stage schedule / publish barriers unchanged from round 6:
// stages ph0->U3(w+1) other buf, ph1..3->U(ph-1)(w+2) cur buf; vmcnt(6) at
// odd slots keeps 3 newest units; tail w>=NT-2 drains vmcnt(0).
// ===========================================================================
template<int K>
__global__ __launch_bounds__(512, 2) void gemm2_8ph(
    const short* __restrict__ A, const short* __restrict__ Bw,
    const float* __restrict__ bias, unsigned short* __restrict__ Cout) {
    constexpr int NT = K / 64;
    constexpr unsigned OFF_A0 = 0, OFF_B0 = 16384, OFF_A1 = 32768, OFF_B1 = 49152;
    __shared__ __align__(16) short smem[65536];   // 128 KB

    const int tid = threadIdx.x;
    const int lane = tid & 63;
    const int wave = tid >> 6;      // 0..7
    const int wm = wave >> 2;       // 0..1  -> 128-row half
    const int wn = wave & 3;        // 0..3  -> 64-col quarter
    const int l15 = lane & 15;
    const int quad = lane >> 4;
    const int srow = lane >> 3;
    const int skb8 = ((lane & 7) ^ srow) << 3;

    const int wgid = xcd_swz(blockIdx.x, gridDim.x);
    const int mt = wgid >> 2, nt = wgid & 3;    // 4 n-tiles (N=1024)
    const size_t Abase = (size_t)(mt * 256) * K;
    const size_t Bbase = (size_t)(nt * 256) * K;

    f32x4 acc[8][4];
#pragma unroll
    for (int m = 0; m < 8; ++m)
#pragma unroll
        for (int n = 0; n < 4; ++n) acc[m][n] = f32x4{0.f, 0.f, 0.f, 0.f};

    bf16x8 af[2][2][2] = {};      // [slot-parity set][mm][kk]; zero-init
    bf16x8 bfr[2][4][2] = {};     // [window-parity set][n][kk]; zero-init

    auto stage2 = [&](unsigned off, const short* g, size_t rowbase, int kc, int c0, int c1) {
        gl2lds16(g + rowbase + (size_t)(c0 * 8 + srow) * K + kc + skb8, smem + off + c0 * 512);
        gl2lds16(g + rowbase + (size_t)(c1 * 8 + srow) * K + kc + skb8, smem + off + c1 * 512);
    };
    auto stageU = [&](int u, unsigned aOff, unsigned bOff, int kc) {
        if (u == 0)      stage2(bOff, Bw, Bbase, kc, wave * 2, wave * 2 + 1);
        else if (u == 1) stage2(bOff, Bw, Bbase, kc, 16 + wave * 2, 17 + wave * 2);
        else if (u == 2) stage2(aOff, A, Abase, kc, wave, 16 + wave);
        else             stage2(aOff, A, Abase, kc, 8 + wave, 24 + wave);
    };

    const unsigned x0 = (unsigned)((quad ^ (l15 & 7)) << 3);          // kk=0
    const unsigned x1 = (unsigned)(((4 + quad) ^ (l15 & 7)) << 3);    // kk=1

    auto mfma8 = [&](int pprev, int aset, int wset) {
        __builtin_amdgcn_s_setprio(1);
#pragma unroll
        for (int kk = 0; kk < 2; ++kk)
#pragma unroll
            for (int mm = 0; mm < 2; ++mm)
#pragma unroll
                for (int n = 0; n < 4; ++n)
                    acc[pprev * 2 + mm][n] = __builtin_amdgcn_mfma_f32_16x16x32_bf16(
                        af[aset][mm][kk], bfr[wset][n][kk], acc[pprev * 2 + mm][n], 0, 0, 0);
        __builtin_amdgcn_s_setprio(0);
    };

    auto slot = [&](int ph, int w, int wpar, unsigned caOff, unsigned cbOff,
                    unsigned naOff, unsigned nbOff) {
        if (ph & 1) {
            if (w < NT - 2) asm volatile("s_waitcnt vmcnt(6)" ::: "memory");
            else            asm volatile("s_waitcnt vmcnt(0)" ::: "memory");
        }
        __builtin_amdgcn_sched_barrier(0);
        __builtin_amdgcn_s_barrier();
        __builtin_amdgcn_sched_barrier(0);
        if (ph == 0) { if (w + 1 < NT) stageU(3, naOff, nbOff, (w + 1) << 6); }
        else         { if (w + 2 < NT) stageU(ph - 1, caOff, cbOff, (w + 2) << 6); }
        __builtin_amdgcn_sched_barrier(0);
        // ---- issue reads for NEXT slot, then wait only for PREV slot's reads
        const short* aA = smem + caOff + ((wm << 7) + l15) * 64;
        const short* aB = smem + cbOff + ((wn << 6) + l15) * 64;
        const int sp = ph & 1;
        if (ph == 0) {
#pragma unroll
            for (int n = 0; n < 4; ++n) {
                bfr[wpar][n][0] = ds_read_b128_asm(aB + n * 1024 + x0);
                bfr[wpar][n][1] = ds_read_b128_asm(aB + n * 1024 + x1);
            }
        }
#pragma unroll
        for (int mm = 0; mm < 2; ++mm) {
            af[sp][mm][0] = ds_read_b128_asm(aA + (ph * 2 + mm) * 1024 + x0);
            af[sp][mm][1] = ds_read_b128_asm(aA + (ph * 2 + mm) * 1024 + x1);
        }
        __builtin_amdgcn_sched_barrier(0);
        if (ph == 0) asm volatile("s_waitcnt lgkmcnt(12)" ::: "memory");
        else         asm volatile("s_waitcnt lgkmcnt(4)" ::: "memory");
        __builtin_amdgcn_sched_barrier(0);
        mfma8((ph + 3) & 3, sp ^ 1, (ph == 0) ? (wpar ^ 1) : wpar);
        __builtin_amdgcn_sched_barrier(0);
    };

    // ---- prologue: tile0 complete -> buf0; tile1 U0..U2 -> buf1
    stageU(0, OFF_A0, OFF_B0, 0);
    stageU(1, OFF_A0, OFF_B0, 0);
    stageU(2, OFF_A0, OFF_B0, 0);
    stageU(3, OFF_A0, OFF_B0, 0);
    stageU(0, OFF_A1, OFF_B1, 64);
    stageU(1, OFF_A1, OFF_B1, 64);
    stageU(2, OFF_A1, OFF_B1, 64);
    asm volatile("s_waitcnt vmcnt(6)" ::: "memory");

#pragma unroll 1
    for (int w = 0; w < NT; w += 2) {
#pragma unroll
        for (int ph = 0; ph < 4; ++ph)
            slot(ph, w, 0, OFF_A0, OFF_B0, OFF_A1, OFF_B1);
#pragma unroll
        for (int ph = 0; ph < 4; ++ph)
            slot(ph, w + 1, 1, OFF_A1, OFF_B1, OFF_A0, OFF_B0);
    }
    // final MFMA: consumes reads of the last slot (ph3, w=NT-1 -> af set 1,
    // bfr window-parity 1)
    asm volatile("s_waitcnt lgkmcnt(0)" ::: "memory");
    __builtin_amdgcn_sched_barrier(0);
    mfma8(3, 1, 1);

    // ---- epilogue: bias+relu -> LDS bf16 (swizzled) -> coalesced store
    __syncthreads();
    unsigned short* cs = (unsigned short*)smem;
#pragma unroll
    for (int n = 0; n < 4; ++n) {
        int colblk = wn * 4 + n;
        int col = (colblk << 4) + l15;
        float bb = bias[nt * 256 + col];
#pragma unroll
        for (int m = 0; m < 8; ++m) {
            int row = (wm << 7) + m * 16 + (quad << 2);
#pragma unroll
            for (int rr = 0; rr < 4; ++rr) {
                int rw = row + rr;
                int sb = colblk ^ ((rw >> 2) & 3);
                cs[rw * 256 + (sb << 4) + l15] = f2bf(fmaxf(acc[m][n][rr] + bb, 0.f));
            }
        }
    }
    __syncthreads();
    const size_t cbase = (size_t)(mt * 256) * 1024 + nt * 256;
    const int rloc = tid >> 5, cchunk = tid & 31;
#pragma unroll
    for (int rnd = 0; rnd < 16; ++rnd) {
        int rw = rnd * 16 + rloc;
        int blk = cchunk >> 1, half = cchunk & 1;
        int sb = blk ^ ((rw >> 2) & 3);
        short8 v = *(const short8*)&cs[rw * 256 + (sb << 4) + half * 8];
        *(short8*)((unsigned short*)Cout + cbase + (size_t)rw * 1024 + cchunk * 8) = v;
    }
}

// ===========================================================================
// GEMM3 + finalize, slot-pipelined (round-7 structure, unchanged).
// ===========================================================================
__global__ __launch_bounds__(512, 2) void gemm3_pipe(
    const short* __restrict__ H2, const short* __restrict__ W3T,
    const float* __restrict__ b3, const float* __restrict__ x,
    float* __restrict__ out, float* __restrict__ logdet) {
    constexpr int K = 1024, NT = 16;
    constexpr unsigned OFF_A0 = 0, OFF_B0 = 8192, OFF_A1 = 24576, OFF_B1 = 32768;
    __shared__ __align__(16) short smem[49152];   // 96 KB
    __shared__ float rowsum[128];

    const int tid = threadIdx.x;
    const int lane = tid & 63;
    const int wave = tid >> 6;      // 0..7
    const int wm = wave >> 2;       // 0..1  -> 64-row half
    const int wn = wave & 3;        // 0..3  -> 64-col quarter
    const int l15 = lane & 15;
    const int quad = lane >> 4;
    const int srow = lane >> 3;
    const int skb8 = ((lane & 7) ^ srow) << 3;

    const int mt = xcd_swz(blockIdx.x, gridDim.x);
    const int tm = mt * 128;
    const size_t Abase = (size_t)tm * K;

    if (tid < 128) rowsum[tid] = 0.f;

    f32x4 acc[4][4];
#pragma unroll
    for (int i = 0; i < 4; ++i)
#pragma unroll
        for (int j = 0; j < 4; ++j) acc[i][j] = f32x4{0.f, 0.f, 0.f, 0.f};

    bf16x8 af[2] = {};
    bf16x8 bfr[4][2] = {};

    auto stage2 = [&](unsigned off, const short* g, size_t rowbase, int kc, int c0, int c1) {
        gl2lds16(g + rowbase + (size_t)(c0 * 8 + srow) * K + kc + skb8, smem + off + c0 * 512);
        gl2lds16(g + rowbase + (size_t)(c1 * 8 + srow) * K + kc + skb8, smem + off + c1 * 512);
    };
    auto stageA  = [&](unsigned aOff, int kc) { stage2(aOff, H2, Abase, kc, wave, 8 + wave); };
    auto stageB1 = [&](unsigned bOff, int kc) { stage2(bOff, W3T, 0, kc, 2 * wave, 2 * wave + 1); };
    auto stageB2 = [&](unsigned bOff, int kc) { stage2(bOff, W3T, 0, kc, 16 + 2 * wave, 17 + 2 * wave); };

    const unsigned x0 = (unsigned)((quad ^ (l15 & 7)) << 3);          // kk=0
    const unsigned x1 = (unsigned)(((4 + quad) ^ (l15 & 7)) << 3);    // kk=1

    auto mfma4 = [&](int pprev) {
        __builtin_amdgcn_s_setprio(1);
#pragma unroll
        for (int kk = 0; kk < 2; ++kk)
#pragma unroll
            for (int n = 0; n < 4; ++n)
                acc[pprev][n] = __builtin_amdgcn_mfma_f32_16x16x32_bf16(
                    af[kk], bfr[n][kk], acc[pprev][n], 0, 0, 0);
        __builtin_amdgcn_s_setprio(0);
    };

    auto slot = [&](int ph, int w, unsigned caOff, unsigned cbOff, unsigned naOff) {
        if (w < NT - 2) asm volatile("s_waitcnt vmcnt(4)" ::: "memory");
        else            asm volatile("s_waitcnt vmcnt(0)" ::: "memory");
        __builtin_amdgcn_sched_barrier(0);
        __builtin_amdgcn_s_barrier();
        __builtin_amdgcn_sched_barrier(0);
        if (ph == 0)      { if (w + 1 < NT) stageA(naOff, (w + 1) << 6); }
        else if (ph == 1) { if (w + 2 < NT) stageB1(cbOff, (w + 2) << 6); }
        else if (ph == 2) { if (w + 2 < NT) stageB2(cbOff, (w + 2) << 6); }
        __builtin_amdgcn_sched_barrier(0);
        asm volatile("s_waitcnt lgkmcnt(0)" ::: "memory");
        __builtin_amdgcn_sched_barrier(0);
        mfma4((ph + 3) & 3);
        __builtin_amdgcn_sched_barrier(0);
        const short* aA = smem + caOff + ((wm << 6) + l15) * 64;
        const short* aB = smem + cbOff + ((wn << 6) + l15) * 64;
        if (ph == 0) {
#pragma unroll
            for (int n = 0; n < 4; ++n) {
                bfr[n][0] = ds_read_b128_asm(aB + n * 1024 + x0);
                bfr[n][1] = ds_read_b128_asm(aB + n * 1024 + x1);
            }
        }
        af[0] = ds_read_b128_asm(aA + ph * 1024 + x0);
        af[1] = ds_read_b128_asm(aA + ph * 1024 + x1);
        __builtin_amdgcn_sched_barrier(0);
    };

    stageA(OFF_A0, 0);
    stageB1(OFF_B0, 0);
    stageB2(OFF_B0, 0);
    stageB1(OFF_B1, 64);
    stageB2(OFF_B1, 64);
    asm volatile("s_waitcnt vmcnt(4)" ::: "memory");

#pragma unroll 1
    for (int w = 0; w < NT; w += 2) {
#pragma unroll
        for (int ph = 0; ph < 4; ++ph)
            slot(ph, w, OFF_A0, OFF_B0, OFF_A1);
#pragma unroll
        for (int ph = 0; ph < 4; ++ph)
            slot(ph, w + 1, OFF_A1, OFF_B1, OFF_A0);
    }
    asm volatile("s_waitcnt lgkmcnt(0)" ::: "memory");
    __builtin_amdgcn_sched_barrier(0);
    mfma4(3);

    // ---- finalize ----
    __syncthreads();
    float* Tbuf = (float*)smem;     // 128 x 132 f32, overlays staging
    if (wn >= 2) {
#pragma unroll
        for (int n = 0; n < 4; ++n) {
            int col = (wn << 6) + n * 16 + l15;   // 128..255
            float bb = b3[col];
            int cl = col - 128;
#pragma unroll
            for (int mm = 0; mm < 4; ++mm) {
#pragma unroll
                for (int rr = 0; rr < 4; ++rr) {
                    int m = (wm << 6) + mm * 16 + quad * 4 + rr;
                    Tbuf[m * 132 + cl] = acc[mm][n][rr] + bb;
                }
            }
        }
    }
    __syncthreads();
    if (wn < 2) {
#pragma unroll
        for (int mm = 0; mm < 4; ++mm) {
#pragma unroll
            for (int rr = 0; rr < 4; ++rr) {
                int m = (wm << 6) + mm * 16 + quad * 4 + rr;
                int grow = tm + m;
                float s = 0.f;
#pragma unroll
                for (int n = 0; n < 4; ++n) {
                    int j = (wn << 6) + n * 16 + l15;   // 0..127
                    float p = acc[mm][n][rr] + b3[j];
                    p = fminf(fmaxf(p, -15.f), 15.f);
                    float e2 = __expf(2.f * p);
                    float ls = (e2 - 1.f) / (e2 + 1.f);  // tanh(p)
                    s += ls;
                    float tt = Tbuf[m * 132 + j];
                    float2 xv = *(const float2*)&x[(size_t)grow * 256 + 2 * j];
                    float2 ov;
                    ov.x = xv.x;
                    ov.y = xv.y * __expf(ls) + tt;
                    *(float2*)&out[(size_t)grow * 256 + 2 * j] = ov;
                }
                s += __shfl_xor(s, 1);
                s += __shfl_xor(s, 2);
                s += __shfl_xor(s, 4);
                s += __shfl_xor(s, 8);
                if (l15 == 0) atomicAdd(&rowsum[m], s);
            }
        }
    }
    __syncthreads();
    if (tid < 128) logdet[tm + tid] = rowsum[tid];
}

extern "C" void kernel_launch(void* const* d_in, const int* in_sizes, int n_in,
                              void* d_out, int out_size, void* d_ws, size_t ws_size,
                              hipStream_t stream) {
    const float* x = (const float*)d_in[0];
    const float* cond = (const float*)d_in[1];
    const float* W1 = (const float*)d_in[2];
    const float* b1 = (const float*)d_in[3];
    const float* W2 = (const float*)d_in[4];
    const float* b2 = (const float*)d_in[5];
    const float* Wsp = (const float*)d_in[6];
    const float* bs = (const float*)d_in[7];
    const float* Wtp = (const float*)d_in[8];
    const float* bt = (const float*)d_in[9];

    char* ws = (char*)d_ws;
    short* W1T = (short*)(ws);                          // 1024x256 bf16 = 512 KB
    short* W2T = (short*)(ws + 524288ull);              // 1024x1024 bf16 = 2 MB
    short* W3T = (short*)(ws + 2621440ull);             // 256x1024 bf16 = 512 KB
    float* b3  = (float*)(ws + 3145728ull);             // 1 KB
    short* Aprep = (short*)(ws + 3149824ull);           // 65536x256 bf16 = 32 MB
    const size_t chunk_base = 3149824ull + 33554432ull;

    int n_chunks = 1;
    while (n_chunks < 512) {
        size_t rp = (size_t)B_ROWS / n_chunks;
        if (chunk_base + rp * 4096ull <= ws_size) break;
        n_chunks *= 2;
    }
    const size_t RP = (size_t)B_ROWS / n_chunks;

    float* out = (float*)d_out;
    float* logdet = out + (size_t)B_ROWS * D_DIM;

    prep_all<<<(196864 + B_ROWS * 32 + 255) / 256, 256, 0, stream>>>(
        W1, W2, Wsp, Wtp, bs, bt, x, cond, W1T, W2T, W3T, b3, Aprep);

    for (int c = 0; c < n_chunks; ++c) {
        const size_t r0 = (size_t)c * RP;
        short* H1 = (short*)(ws + chunk_base);
        short* H2 = (short*)(ws + chunk_base + 2048ull * RP);
        const int mtiles = (int)(RP / 128);

        if ((RP & 255) == 0) {
            gemm2_8ph<256><<<(int)(RP / 256) * 4, 512, 0, stream>>>(
                Aprep + r0 * 256, W1T, b1, (unsigned short*)H1);
            gemm2_8ph<1024><<<(int)(RP / 256) * 4, 512, 0, stream>>>(
                H1, W2T, b2, (unsigned short*)H2);
        } else {
            gemm_tn<<<mtiles * 8, 256, 0, stream>>>(
                Aprep + r0 * 256, W1T, b1, (unsigned short*)H1, mtiles, H_DIM, 256);
            gemm_tn<<<mtiles * 8, 256, 0, stream>>>(
                H1, W2T, b2, (unsigned short*)H2, mtiles, H_DIM, H_DIM);
        }
        gemm3_pipe<<<(int)(RP / 128), 512, 0, stream>>>(
            H2, W3T, b3, x + r0 * D_DIM, out + r0 * D_DIM, logdet + r0);
    }
}